// Round 1
// baseline (2247.770 us; speedup 1.0000x reference)
//
#include <hip/hip_runtime.h>
#include <stdint.h>

#define DM    4096
#define SEQL  2048
#define NHEAD 16
#define DHEAD 256
#define NP    28672   // 7*DM  (proj cols: q | v | k | ff)
#define KA    20480   // 5*DM  (A2 cols: attn | gelu(ff))

typedef __attribute__((ext_vector_type(8))) short    bf16x8;
typedef __attribute__((ext_vector_type(4))) float    f32x4;
typedef __attribute__((ext_vector_type(4))) uint32_t u32x4;

__device__ __forceinline__ void gload16(const void* g, void* l) {
  __builtin_amdgcn_global_load_lds(
      (const __attribute__((address_space(1))) uint32_t*)g,
      (__attribute__((address_space(3))) uint32_t*)l, 16, 0, 0);
}
__device__ __forceinline__ unsigned short f2bf(float f) {
  uint32_t u = __builtin_bit_cast(uint32_t, f);
  u = (u + 0x7fffu + ((u >> 16) & 1u)) >> 16;
  return (unsigned short)u;
}
__device__ __forceinline__ float bf2f(unsigned short h) {
  return __builtin_bit_cast(float, (uint32_t)h << 16);
}
__device__ __forceinline__ float gelu1(float x) {
  float u = 0.7978845608028654f * (x + 0.044715f * x * x * x);
  float e = __expf(2.f * u);                  // inf/0 both give tanh=+-1
  return 0.5f * x * (1.f + (1.f - 2.f / (e + 1.f)));
}

// ---------------- LayerNorm -> bf16 ----------------
__global__ __launch_bounds__(256)
void ln_kernel(const float* __restrict__ x, const float* __restrict__ sc,
               const float* __restrict__ off, unsigned short* __restrict__ xn) {
  const int row = blockIdx.x, t = threadIdx.x;
  const float4* xr = (const float4*)(x + (size_t)row * DM);
  float4 v[4];
  float s = 0.f, s2 = 0.f;
#pragma unroll
  for (int i = 0; i < 4; ++i) {
    v[i] = xr[t + i*256];
    s  += v[i].x + v[i].y + v[i].z + v[i].w;
    s2 += v[i].x*v[i].x + v[i].y*v[i].y + v[i].z*v[i].z + v[i].w*v[i].w;
  }
#pragma unroll
  for (int m = 1; m < 64; m <<= 1) { s += __shfl_xor(s, m); s2 += __shfl_xor(s2, m); }
  __shared__ float red[8];
  if ((t & 63) == 0) { red[t >> 6] = s; red[4 + (t >> 6)] = s2; }
  __syncthreads();
  s  = red[0] + red[1] + red[2] + red[3];
  s2 = red[4] + red[5] + red[6] + red[7];
  const float mean = s * (1.f / DM);
  const float inv  = rsqrtf(s2 * (1.f / DM) - mean*mean + 1e-5f);
  unsigned short* orow = xn + (size_t)row * DM;
#pragma unroll
  for (int i = 0; i < 4; ++i) {
    const int u = t + i*256;
    const float4 s4 = ((const float4*)sc)[u];
    const float4 o4 = ((const float4*)off)[u];
    uint32_t w0 = (uint32_t)f2bf((v[i].x - mean)*inv*s4.x + o4.x)
                | ((uint32_t)f2bf((v[i].y - mean)*inv*s4.y + o4.y) << 16);
    uint32_t w1 = (uint32_t)f2bf((v[i].z - mean)*inv*s4.z + o4.z)
                | ((uint32_t)f2bf((v[i].w - mean)*inv*s4.w + o4.w) << 16);
    *(uint2*)(orow + u*4) = make_uint2(w0, w1);
  }
}

// -------- fp32 [K][N] -> bf16 [N][K] transpose-convert --------
__global__ __launch_bounds__(256)
void tcvt_kernel(const float* __restrict__ in, unsigned short* __restrict__ out,
                 const int K, const int N) {
  __shared__ unsigned short tl[64][72];   // [n][k], 144B rows (16B aligned)
  const int k0 = blockIdx.x * 64, n0 = blockIdx.y * 64;
  const int t = threadIdx.x;
#pragma unroll
  for (int i = 0; i < 4; ++i) {
    const int task = t + i*256;
    const int k = task >> 4, n4 = (task & 15) * 4;
    const float4 f = *(const float4*)(in + (size_t)(k0 + k)*N + n0 + n4);
    tl[n4+0][k] = f2bf(f.x);
    tl[n4+1][k] = f2bf(f.y);
    tl[n4+2][k] = f2bf(f.z);
    tl[n4+3][k] = f2bf(f.w);
  }
  __syncthreads();
#pragma unroll
  for (int i = 0; i < 2; ++i) {
    const int task = t + i*256;
    const int n = task >> 3, k8 = (task & 7) * 8;
    *(u32x4*)(out + (size_t)(n0 + n)*K + k0 + k8) = *(const u32x4*)&tl[n][k8];
  }
}

// -------- MFMA GEMM: C[M][N] = A[M][K](bf16) x BT[N][K](bf16) + bias --------
// m97 structure: 128x128 tile, BK=32, 4 waves 2x2, global_load_lds w=16.
template<int OUTMODE>   // 0: bf16 out, 1: fp32 out
__global__ __launch_bounds__(256, 2)
void gemm_bt(const unsigned short* __restrict__ A, const unsigned short* __restrict__ BT,
             const float* __restrict__ bias, void* __restrict__ Cout,
             const int N, const int K) {
  __shared__ unsigned short As[128][32];
  __shared__ unsigned short Bs[128][32];
  const int tid = threadIdx.x;
  const int m0 = blockIdx.x * 128, n0 = blockIdx.y * 128;
  const int wave = tid >> 6, lane = tid & 63;
  const int wr = (wave >> 1) * 64, wc = (wave & 1) * 64;
  const int lrow = lane & 15, lk = (lane >> 4) * 8;
  f32x4 acc[4][4] = {};
  const int r1 = tid >> 2, s1 = (tid & 3) * 8;
  const unsigned short* gA = A  + (size_t)(m0 + r1) * K + s1;
  const unsigned short* gB = BT + (size_t)(n0 + r1) * K + s1;
  for (int k0 = 0; k0 < K; k0 += 32) {
    __syncthreads();
    gload16(gA + k0,                &As[r1][s1]);
    gload16(gA + k0 + (size_t)64*K, &As[r1 + 64][s1]);
    gload16(gB + k0,                &Bs[r1][s1]);
    gload16(gB + k0 + (size_t)64*K, &Bs[r1 + 64][s1]);
    __syncthreads();   // includes vmcnt(0): global_load_lds landed
    bf16x8 av[4], bv[4];
#pragma unroll
    for (int i = 0; i < 4; ++i) {
      av[i] = *(const bf16x8*)&As[wr + i*16 + lrow][lk];
      bv[i] = *(const bf16x8*)&Bs[wc + i*16 + lrow][lk];
    }
#pragma unroll
    for (int mi = 0; mi < 4; ++mi)
#pragma unroll
      for (int ni = 0; ni < 4; ++ni)
        acc[mi][ni] = __builtin_amdgcn_mfma_f32_16x16x32_bf16(av[mi], bv[ni], acc[mi][ni], 0, 0, 0);
  }
  // C/D layout (m89-verified): row=(lane>>4)*4+reg, col=lane&15
  const int er = m0 + wr + (lane >> 4) * 4;
  const int ec = n0 + wc + lrow;
#pragma unroll
  for (int ni = 0; ni < 4; ++ni) {
    const int cc = ec + ni*16;
    const float b = bias[cc];
#pragma unroll
    for (int mi = 0; mi < 4; ++mi)
#pragma unroll
      for (int r = 0; r < 4; ++r) {
        const float vv = acc[mi][ni][r] + b;
        const size_t idx = (size_t)(er + mi*16 + r) * N + cc;
        if (OUTMODE == 0) ((unsigned short*)Cout)[idx] = f2bf(vv);
        else              ((float*)Cout)[idx] = vv;
      }
  }
}

// ---------------- RoPE in-place on q,k (first 64 dims/head) ----------------
__global__ __launch_bounds__(256)
void rope_kernel(unsigned short* __restrict__ proj) {
  const int id = blockIdx.x * 256 + threadIdx.x;  // SEQL*2*16*32 threads
  const int pair  = id & 31;
  const int head  = (id >> 5) & 15;
  const int which = (id >> 9) & 1;                // 0: q(col 0), 1: k(col 2*DM)
  const int tok   = id >> 10;
  unsigned short* p = proj + (size_t)tok*NP + which*(2*DM) + head*DHEAD + pair*2;
  uint32_t u = *(uint32_t*)p;
  float x1 = bf2f((unsigned short)(u & 0xffffu));
  float x2 = bf2f((unsigned short)(u >> 16));
  float freq = exp2f((float)pair * (-13.287712379549449f / 32.f)); // 10000^(-p/32)
  float sn, cs;
  sincosf((float)tok * freq, &sn, &cs);
  float o1 = x1*cs - x2*sn;
  float o2 = x2*cs + x1*sn;
  *(uint32_t*)p = (uint32_t)f2bf(o1) | ((uint32_t)f2bf(o2) << 16);
}

// ---------------- GELU: proj ff -> A2 right half ----------------
__global__ __launch_bounds__(256)
void gelu_kernel(const unsigned short* __restrict__ proj, unsigned short* __restrict__ A2) {
  const int id  = blockIdx.x * 256 + threadIdx.x;   // SEQL*2048 chunks of 8
  const int row = id >> 11;
  const int c8  = (id & 2047) * 8;
  u32x4 v = *(const u32x4*)(proj + (size_t)row*NP + 3*DM + c8);
  uint32_t o[4];
#pragma unroll
  for (int j = 0; j < 4; ++j) {
    float x0 = bf2f((unsigned short)(v[j] & 0xffffu));
    float x1 = bf2f((unsigned short)(v[j] >> 16));
    o[j] = (uint32_t)f2bf(gelu1(x0)) | ((uint32_t)f2bf(gelu1(x1)) << 16);
  }
  *(u32x4*)(A2 + (size_t)row*KA + DM + c8) = (u32x4){o[0], o[1], o[2], o[3]};
}

// ---------------- Flash attention ----------------
// block = (q-tile of 64 rows, head). 4 waves x 16 q-rows each.
__global__ __launch_bounds__(256, 1)
void attn_kernel(const unsigned short* __restrict__ proj,
                 const float* __restrict__ bias,
                 unsigned short* __restrict__ A2) {
  const int qb = blockIdx.x;       // 0..31
  const int h  = blockIdx.y;       // 0..15
  const int tid = threadIdx.x;
  const int wave = tid >> 6, lane = tid & 63;
  const int lrow = lane & 15;
  const int lgrp = lane >> 4;
  const int lk = lgrp << 3;

  __shared__ unsigned short Kl[64*256];      // [key][d] bf16, XOR-swizzled, 32KB
  __shared__ unsigned short Vt[256*64];      // [d][key] bf16, XOR-swizzled, 32KB
  __shared__ float          Sl[4][16][68];   // per-wave S rows
  __shared__ unsigned short Pl[4][16][72];   // per-wave P rows (144B stride)
  __shared__ float          scl[4][16];
  __shared__ float          ll[4][16];

  // Q fragments (A-operand): row = lane&15, k = 8*(lane>>4)+j
  const int qrow = qb*64 + wave*16 + lrow;
  bf16x8 qf[8];
#pragma unroll
  for (int c = 0; c < 8; ++c)
    qf[c] = *(const bf16x8*)&proj[(size_t)qrow*NP + h*DHEAD + c*32 + lk];

  f32x4 oacc[16];
#pragma unroll
  for (int i = 0; i < 16; ++i) oacc[i] = (f32x4){0.f, 0.f, 0.f, 0.f};
  float m_r = -1e30f, l_r = 0.f;

  const int sr = lrow, sg = lgrp;           // softmax mapping: 4 lanes per q-row
  const int q_sm = qb*64 + wave*16 + sr;

  for (int kt = 0; kt <= qb; ++kt) {
    // ---- V global loads to regs (issue before barrier; regs only) ----
    uint32_t vreg[4][8];
#pragma unroll
    for (int i = 0; i < 4; ++i) {
      const int task = tid + i*256;
      const int dpair = task & 127, koct = task >> 7;
      const size_t gb = (size_t)(kt*64 + koct*8)*NP + DM + h*DHEAD + dpair*2;
#pragma unroll
      for (int j = 0; j < 8; ++j)
        vreg[i][j] = *(const uint32_t*)&proj[gb + (size_t)j*NP];
    }
    __syncthreads();   // prev-iter PV done: Kl/Vt reusable
    // ---- K staging: linear LDS dest, inverse-swizzled global source ----
#pragma unroll
    for (int i = 0; i < 8; ++i) {
      const int u = tid + i*256;
      const int kr = u >> 5, seg = u & 31;
      const int gs = seg ^ (kr & 7);
      gload16(&proj[(size_t)(kt*64 + kr)*NP + 2*DM + h*DHEAD + gs*8],
              &Kl[kr*256 + seg*8]);
    }
    // ---- V repack (2 d per thread) + swizzled ds_write_b128 ----
#pragma unroll
    for (int i = 0; i < 4; ++i) {
      const int task = tid + i*256;
      const int dpair = task & 127, koct = task >> 7;
      uint32_t lo[4], hi[4];
#pragma unroll
      for (int j = 0; j < 4; ++j) {
        const uint32_t a = vreg[i][2*j], b = vreg[i][2*j+1];
        lo[j] = (a & 0xffffu) | (b << 16);
        hi[j] = (a >> 16)     | (b & 0xffff0000u);
      }
      const int d0 = dpair*2;
      const int alo = (d0*128 + koct*16)       ^ ((d0 & 7) << 4);
      const int ahi = ((d0+1)*128 + koct*16)   ^ (((d0+1) & 7) << 4);
      *(u32x4*)((char*)Vt + alo) = (u32x4){lo[0], lo[1], lo[2], lo[3]};
      *(u32x4*)((char*)Vt + ahi) = (u32x4){hi[0], hi[1], hi[2], hi[3]};
    }
    __syncthreads();   // K landed (vmcnt0) + V writes visible
    // ---- QK^T: S[16q][64key] per wave ----
    f32x4 sacc[4];
#pragma unroll
    for (int s = 0; s < 4; ++s) sacc[s] = (f32x4){0.f, 0.f, 0.f, 0.f};
#pragma unroll
    for (int c = 0; c < 8; ++c)
#pragma unroll
      for (int s = 0; s < 4; ++s) {
        const int row = s*16 + lrow;
        const int byt = (row*512 + c*64 + lk*2) ^ ((row & 7) << 4);
        bf16x8 kf = *(const bf16x8*)((const char*)Kl + byt);
        sacc[s] = __builtin_amdgcn_mfma_f32_16x16x32_bf16(qf[c], kf, sacc[s], 0, 0, 0);
      }
#pragma unroll
    for (int s = 0; s < 4; ++s)
#pragma unroll
      for (int r = 0; r < 4; ++r)
        Sl[wave][lgrp*4 + r][s*16 + lrow] = sacc[s][r];
    // ---- online softmax (in-wave DS ordering: write then read, same wave) ----
    float sv[16];
    const float* brow = bias + (size_t)q_sm*SEQL + kt*64 + sg*16;
    const int kb = kt*64 + sg*16;
#pragma unroll
    for (int i4 = 0; i4 < 4; ++i4) {
      const float4 b4 = *(const float4*)(brow + i4*4);
      const float bb[4] = {b4.x, b4.y, b4.z, b4.w};
#pragma unroll
      for (int j = 0; j < 4; ++j) {
        const int i = i4*4 + j;
        float s = Sl[wave][sr][sg*16 + i] * 0.0625f + bb[j];
        if (kb + i > q_sm) s = -1e10f;
        sv[i] = s;
      }
    }
    float mx = sv[0];
#pragma unroll
    for (int i = 1; i < 16; ++i) mx = fmaxf(mx, sv[i]);
    mx = fmaxf(mx, __shfl_xor(mx, 16));
    mx = fmaxf(mx, __shfl_xor(mx, 32));
    const float mnew = fmaxf(m_r, mx);
    const float scf = __expf(m_r - mnew);
    float ps = 0.f;
    uint32_t pw[8];
#pragma unroll
    for (int i2 = 0; i2 < 8; ++i2) {
      const float p0 = __expf(sv[2*i2]   - mnew);
      const float p1 = __expf(sv[2*i2+1] - mnew);
      ps += p0 + p1;
      pw[i2] = (uint32_t)f2bf(p0) | ((uint32_t)f2bf(p1) << 16);
    }
    ps += __shfl_xor(ps, 16);
    ps += __shfl_xor(ps, 32);
    l_r = l_r * scf + ps;
    m_r = mnew;
    *(u32x4*)&Pl[wave][sr][sg*16]     = (u32x4){pw[0], pw[1], pw[2], pw[3]};
    *(u32x4*)&Pl[wave][sr][sg*16 + 8] = (u32x4){pw[4], pw[5], pw[6], pw[7]};
    if (sg == 0) scl[wave][sr] = scf;
    __syncthreads();   // P + scale visible
    // ---- rescale O, then PV ----
    float osc[4];
#pragma unroll
    for (int r = 0; r < 4; ++r) osc[r] = scl[wave][lgrp*4 + r];
#pragma unroll
    for (int dt = 0; dt < 16; ++dt)
#pragma unroll
      for (int r = 0; r < 4; ++r) oacc[dt][r] *= osc[r];
#pragma unroll
    for (int kc = 0; kc < 2; ++kc) {
      const bf16x8 pf = *(const bf16x8*)&Pl[wave][lrow][kc*32 + lk];
#pragma unroll
      for (int dt = 0; dt < 16; ++dt) {
        const int d = dt*16 + lrow;
        const int byt = (d*128 + kc*64 + lk*2) ^ ((d & 7) << 4);
        bf16x8 vf = *(const bf16x8*)((const char*)Vt + byt);
        oacc[dt] = __builtin_amdgcn_mfma_f32_16x16x32_bf16(pf, vf, oacc[dt], 0, 0, 0);
      }
    }
  }
  if (sg == 0) ll[wave][sr] = l_r;
  __syncthreads();
  float li[4];
#pragma unroll
  for (int r = 0; r < 4; ++r) li[r] = 1.f / ll[wave][lgrp*4 + r];
#pragma unroll
  for (int dt = 0; dt < 16; ++dt)
#pragma unroll
    for (int r = 0; r < 4; ++r) {
      const int orow = qb*64 + wave*16 + lgrp*4 + r;
      A2[(size_t)orow*KA + h*DHEAD + dt*16 + lrow] = f2bf(oacc[dt][r] * li[r]);
    }
}

// ---------------- launch ----------------
extern "C" void kernel_launch(void* const* d_in, const int* in_sizes, int n_in,
                              void* d_out, int out_size, void* d_ws, size_t ws_size,
                              hipStream_t stream) {
  const float* x     = (const float*)d_in[0];
  const float* ab    = (const float*)d_in[1];
  const float* lsc   = (const float*)d_in[2];
  const float* loff  = (const float*)d_in[3];
  const float* w_in  = (const float*)d_in[4];
  const float* b_in  = (const float*)d_in[5];
  const float* w_out = (const float*)d_in[6];
  const float* b_out = (const float*)d_in[7];
  float* out = (float*)d_out;

  char* ws = (char*)d_ws;
  const size_t MB = 1024ull*1024ull;
  unsigned short* xn   = (unsigned short*)(ws);              // 16 MB
  unsigned short* wT   = (unsigned short*)(ws + 16*MB);      // 224 MB (wT1, reused for wT2)
  unsigned short* proj = (unsigned short*)(ws + 240*MB);     // 112 MB
  unsigned short* A2   = (unsigned short*)(ws + 352*MB);     // 80 MB  -> total 432 MB

  ln_kernel<<<SEQL, 256, 0, stream>>>(x, lsc, loff, xn);
  tcvt_kernel<<<dim3(DM/64, NP/64), 256, 0, stream>>>(w_in, wT, DM, NP);
  gemm_bt<0><<<dim3(SEQL/128, NP/128), 256, 0, stream>>>(xn, wT, b_in, proj, NP, DM);
  rope_kernel<<<(SEQL*1024)/256, 256, 0, stream>>>(proj);
  gelu_kernel<<<(SEQL*2048)/256, 256, 0, stream>>>(proj, A2);
  attn_kernel<<<dim3(SEQL/64, NHEAD), 256, 0, stream>>>(proj, ab, A2);
  tcvt_kernel<<<dim3(KA/64, DM/64), 256, 0, stream>>>(w_out, wT, KA, DM);
  gemm_bt<1><<<dim3(SEQL/128, DM/128), 256, 0, stream>>>(A2, wT, b_out, out, DM, KA);
}